// Round 10
// baseline (1556.713 us; speedup 1.0000x reference)
//
#include <hip/hip_runtime.h>
#include <hip/hip_bf16.h>

// B=1024, L=128, W=512, S=8, STEPS=12, VOCAB=32, NLAB=10

typedef unsigned short u16;
typedef __attribute__((ext_vector_type(8))) short short8;   // 8 x bf16
typedef __attribute__((ext_vector_type(4))) float f32x4;

__device__ __forceinline__ float bf2f(u16 v) {
    union { unsigned int u; float f; } x; x.u = ((unsigned int)v) << 16; return x.f;
}
__device__ __forceinline__ u16 f2bf(float f) {
    union { float f; unsigned int u; } x; x.f = f;
    unsigned int u = x.u;
    return (u16)((u + 0x7FFFu + ((u >> 16) & 1u)) >> 16);   // RNE
}
// Fast transcendentals: v_exp/v_log/v_cos/v_rcp HW ops (~1e-6 err << bf16 eps)
__device__ __forceinline__ float fsig(float v) {
    return __builtin_amdgcn_rcpf(1.f + __expf(-v));
}
__device__ __forceinline__ float ftanh(float v) {
    return 1.f - 2.f * __builtin_amdgcn_rcpf(__expf(2.f * v) + 1.f);
}
__device__ __forceinline__ float fsoftplus(float v) {
    return (v > 20.f) ? v : __logf(1.f + __expf(v));
}

union U4 { ushort4 v; u16 e[4]; };

// Async global->LDS, 16B/lane. LDS dest = wave-uniform base + lane*16.
__device__ __forceinline__ void gload_lds16(const u16* g, u16* l) {
    __builtin_amdgcn_global_load_lds(
        (const __attribute__((address_space(1))) unsigned int*)g,
        (__attribute__((address_space(3))) unsigned int*)l, 16, 0, 0);
}

// ---------------------------------------------------------------------------
// Input-dtype detection (bf16 vs f32 inputs).
// ---------------------------------------------------------------------------
__device__ __forceinline__ int sane16(u16 u) {
    if ((u & 0x7FFF) == 0) return 1;
    int e = (u >> 7) & 0xFF;
    return (e >= 0x33 && e <= 0x43) ? 1 : 0;
}
__global__ __launch_bounds__(256) void detect_k(const u16* __restrict__ raw,
                                                int* __restrict__ flag) {
    const int t = threadIdx.x;
    int c = sane16(raw[1024 + t * 2]) + sane16(raw[1024 + t * 2 + 1]);
#pragma unroll
    for (int off = 32; off; off >>= 1) c += __shfl_down(c, off, 64);
    __shared__ int red[4];
    if ((t & 63) == 0) red[t >> 6] = c;
    __syncthreads();
    if (t == 0) *flag = (red[0] + red[1] + red[2] + red[3] >= 448) ? 1 : 0;
}

// ---------------------------------------------------------------------------
// Canonicalize float tensors to bf16, vectorized.
// ---------------------------------------------------------------------------
struct CT { const void* src[20]; int n[20]; int off[20]; };
__global__ __launch_bounds__(256) void conv_k(CT ct, u16* __restrict__ dstBase,
                                              const int* __restrict__ flag) {
    const int isbf = *flag;
    const int gid = blockIdx.x * 256 + threadIdx.x;
    const int stride = gridDim.x * 256;
    for (int tn = 0; tn < 20; ++tn) {
        const int n = ct.n[tn];
        const int n4 = n >> 2;
        u16* dst = dstBase + ct.off[tn];
        if (!isbf) {
            const float* s = (const float*)ct.src[tn];
            for (int i = gid; i < n4; i += stride) {
                f32x4 v = *(const f32x4*)(s + i * 4);
                *(ushort4*)(dst + i * 4) =
                    make_ushort4(f2bf(v[0]), f2bf(v[1]), f2bf(v[2]), f2bf(v[3]));
            }
            if (gid < (n & 3)) { int i = n4 * 4 + gid; dst[i] = f2bf(s[i]); }
        } else {
            const u16* s = (const u16*)ct.src[tn];
            for (int i = gid; i < n4; i += stride)
                *(ushort4*)(dst + i * 4) = *(const ushort4*)(s + i * 4);
            if (gid < (n & 3)) { int i = n4 * 4 + gid; dst[i] = s[i]; }
        }
    }
}

// ---------------------------------------------------------------------------
// Pack Wcat[s][g][0:512]=W_ih[s][g][:], [512:1024]=W_hh[s][g][:]  (one-time)
// ---------------------------------------------------------------------------
__global__ __launch_bounds__(256) void pack_k(const u16* __restrict__ Wih,
                                              const u16* __restrict__ Whh,
                                              u16* __restrict__ Wcat) {
    long i = ((long)blockIdx.x * 256 + threadIdx.x) * 8;   // over 8*1536*512
    if (i >= 8L * 1536 * 512) return;
    long sg = i >> 9;
    long k  = i & 511;
    *(short8*)(Wcat + sg * 1024 + k)       = *(const short8*)(Wih + i);
    *(short8*)(Wcat + sg * 1024 + 512 + k) = *(const short8*)(Whh + i);
}

// ---------------------------------------------------------------------------
// Batched GEMM params (shared by gemm_k and gemm8_k).
// ---------------------------------------------------------------------------
struct GP {
    const u16* A;  long lda; long aOff[8];
    const u16* Bw; long ldb; long bwOff[8];
    const u16* bias; long biasOff[8];
    const u16* add; long ldadd; long addOff;
    const float* gate_pre;                      // EPI 3
    const u16* bgate;                           // EPI 3
    void* C; long ldc; long cOff[8];
    float* C2;                                  // EPI 4
    u16* C3;                                    // EPI 4
    int K; int nt;
};

// ---------------------------------------------------------------------------
// Legacy batched GEMM (R3-proven 2-buffer), used only for the K=1536
// prologue mix (EPI 4, one dispatch).
// ---------------------------------------------------------------------------
template<int EPI, int MT, int SWZ>
__global__ __launch_bounds__(256) void gemm_k(GP p) {
    constexpr int MW   = MT / 32;   // m-tiles per wave
    constexpr int AITS = MT / 32;   // A staging iterations
    __shared__ __align__(16) u16 lA[2][MT * 64];
    __shared__ __align__(16) u16 lB[2][128 * 64];
    const int t    = threadIdx.x;
    const int lane = t & 63;
    const int wv   = t >> 6;
    int bx = blockIdx.x, byy = blockIdx.y;
    if (SWZ) {
        int wgid = bx + (byy << 5);
        bx  = ((wgid & 7) << 2) + ((wgid >> 3) & 3);
        byy = wgid >> 5;
    }
    const int z    = bx / p.nt;
    const int n0   = (bx - z * p.nt) * 128;
    const int m0   = byy * MT;

    const u16* Ab = p.A + p.aOff[z] + (long)m0 * p.lda;
    const u16* Bb = p.Bw + p.bwOff[z] + (long)n0 * p.ldb;

    f32x4 acc[MW][4];
#pragma unroll
    for (int i = 0; i < MW; i++)
#pragma unroll
        for (int j = 0; j < 4; j++) acc[i][j] = (f32x4){0.f, 0.f, 0.f, 0.f};

    const int wm   = (wv & 1) * (MT / 2);
    const int wn   = (wv >> 1) * 64;
    const int fr   = lane & 15;
    const int quad = lane >> 4;

    auto stage = [&](int buf, long kb) {
#pragma unroll
        for (int it = 0; it < AITS; ++it) {
            int flat = it * 256 + t, row = flat >> 3, src = (flat & 7) ^ (row & 7);
            gload_lds16(Ab + (long)row * p.lda + kb + src * 8, &lA[buf][flat * 8]);
        }
#pragma unroll
        for (int it = 0; it < 4; ++it) {
            int flat = it * 256 + t, row = flat >> 3, src = (flat & 7) ^ (row & 7);
            gload_lds16(Bb + (long)row * p.ldb + kb + src * 8, &lB[buf][flat * 8]);
        }
    };
    auto inner = [&](int cur) {
#pragma unroll
        for (int kk = 0; kk < 2; ++kk) {
            const int q = kk * 4 + quad;
            short8 aF[MW], bF[4];
#pragma unroll
            for (int mi = 0; mi < MW; mi++) {
                int row = wm + mi * 16 + fr;
                aF[mi] = *(const short8*)&lA[cur][row * 64 + (q ^ (row & 7)) * 8];
            }
#pragma unroll
            for (int ni = 0; ni < 4; ni++) {
                int row = wn + ni * 16 + fr;
                bF[ni] = *(const short8*)&lB[cur][row * 64 + (q ^ (row & 7)) * 8];
            }
#pragma unroll
            for (int mi = 0; mi < MW; mi++)
#pragma unroll
                for (int ni = 0; ni < 4; ni++)
                    acc[mi][ni] = __builtin_amdgcn_mfma_f32_16x16x32_bf16(
                        aF[mi], bF[ni], acc[mi][ni], 0, 0, 0);
        }
    };

    const int nk = p.K >> 6;
    stage(0, 0);
    __syncthreads();
    for (int kt = 0; kt < nk; ++kt) {
        const int cur = kt & 1, nxt = cur ^ 1;
        if (kt + 1 < nk) stage(nxt, (long)(kt + 1) * 64);
        inner(cur);
        __syncthreads();
    }

    // Epilogue: D row = quad*4+reg, col = lane&15
#pragma unroll
    for (int mi = 0; mi < MW; mi++) {
#pragma unroll
        for (int ni = 0; ni < 4; ni++) {
            const int mg = m0 + wm + mi * 16 + quad * 4;
            const int ng = n0 + wn + ni * 16 + fr;
#pragma unroll
            for (int r = 0; r < 4; r++) {
                float v = acc[mi][ni][r];
                const long row = mg + r;
                if (EPI == 4) {        // encode mix: h_b, summ_b, h(f32)
                    v = ftanh(v + bf2f(p.bias[ng]));
                    u16 b = f2bf(v);
                    ((u16*)p.C)[row * 512 + ng] = b;
                    p.C3[row * 512 + ng] = b;
                    p.C2[row * 512 + ng] = v;
                }
            }
        }
    }
}

// ---------------------------------------------------------------------------
// gemm8_k — R9: the grug-proven 3-phase schedule ported to the K=512 GEMM
// fleet (EPI 1/3/6/7). Same proven quadrant: 128x128 block, 8 waves (2Mx4N,
// 512 thr), 1 block/CU (grid 256), 3-buffer A+B (48 KB), counted vmcnt
// never 0 in loop, setprio around each MFMA cluster. 2 phases per kt
// (BK=32, nk=16):
//   P1: ds_read aF[4]+bF0; issue stageA(kt+2); bar; lgkmcnt(0); prio1;
//       4 MFMA acc[*][0]; prio0; bar
//   P2: ds_read bF1; issue stageB(kt+2); vmcnt(2)+lgkmcnt(0)
//       [kt=14: vmcnt(0); kt=15: lgkm only]; prio1; 4 MFMA acc[*][1];
//       prio0; bar
// vmcnt ledger (2 gloads/thread/kt, order A,B): at P2-end queue =
// A(kt+1),B(kt+1),A(kt+2),B(kt+2) -> vmcnt(2) lands kt+1's pair, kt+2
// flies across the barrier. WAR: buffer (cur+2)%3 was read at kt-1,
// closed by kt-1's lgkmcnt(0)+final barrier (same proof as grug R9).
// Block mapping = grug's: zc=wgid&7 -> one weight slab per XCD (nt=4);
// bijective shuffle for nt=32. ct = zc*4 + ((wgid>>3)&3), m0=(wgid>>5)*128.
// ---------------------------------------------------------------------------
template<int EPI>
__global__ __launch_bounds__(512, 2) void gemm8_k(GP p) {
    __shared__ __align__(16) u16 lA[3][128 * 32];   // 24 KB
    __shared__ __align__(16) u16 lB[3][128 * 32];   // 24 KB
    const int t    = threadIdx.x;
    const int lane = t & 63;
    const int wv   = t >> 6;           // 0..7
    const int wgid = blockIdx.x + (blockIdx.y << 5);   // grid (32,8)
    const int zc   = wgid & 7;
    const int ct   = zc * 4 + ((wgid >> 3) & 3);       // col tile 0..31
    const int m0   = (wgid >> 5) * 128;
    const int z    = ct / p.nt;
    const int n0   = (ct - z * p.nt) * 128;
    const int fr   = lane & 15;
    const int quad = lane >> 4;
    const int wm   = (wv & 1) * 64;    // wave's m-range (64 rows of 128)
    const int wn   = (wv >> 1) * 32;   // wave's n-range (32 cols of 128)

    const u16* Ab = p.A + p.aOff[z] + (long)m0 * p.lda;
    const u16* Bb = p.Bw + p.bwOff[z] + (long)n0 * p.ldb;

    f32x4 acc[4][2];
#pragma unroll
    for (int mi = 0; mi < 4; mi++)
#pragma unroll
        for (int ni = 0; ni < 2; ni++) acc[mi][ni] = (f32x4){0.f, 0.f, 0.f, 0.f};

    // Staging (512 threads): 128x32 tile = 1 gload/thread. 64B rows,
    // swizzle f(row)=(row>>1)&3 (grug-proven, 0 conflicts).
    const int arow = t >> 2, ac4 = t & 3, asrc = ac4 ^ ((arow >> 1) & 3);

    auto stageA = [&](int buf, int kt) {
        gload_lds16(Ab + (long)arow * p.lda + kt * 32 + asrc * 8, &lA[buf][t * 8]);
    };
    auto stageB = [&](int buf, int kt) {
        gload_lds16(Bb + (long)arow * p.ldb + kt * 32 + asrc * 8, &lB[buf][t * 8]);
    };

    // Prologue: tiles 0,1 in flight; wait for tile 0 (oldest 2 of 4).
    stageA(0, 0); stageB(0, 0); stageA(1, 1); stageB(1, 1);
    asm volatile("s_waitcnt vmcnt(2)" ::: "memory");
    __builtin_amdgcn_s_barrier();

    int cur = 0;
    for (int kt = 0; kt < 16; ++kt) {
        int nx2 = cur + 2; if (nx2 >= 3) nx2 -= 3;
        short8 aF[4], bF0, bF1;

        // ---------------- P1: aF + bF0 ----------------
#pragma unroll
        for (int mi = 0; mi < 4; mi++) {
            int row = wm + mi * 16 + fr;
            aF[mi] = *(const short8*)&lA[cur][row * 32 + ((quad ^ ((row >> 1) & 3)) & 3) * 8];
        }
        {
            int row = wn + fr;
            bF0 = *(const short8*)&lB[cur][row * 32 + ((quad ^ ((row >> 1) & 3)) & 3) * 8];
        }
        if (kt + 2 < 16) stageA(nx2, kt + 2);
        __builtin_amdgcn_s_barrier();
        asm volatile("s_waitcnt lgkmcnt(0)" ::: "memory");
        __builtin_amdgcn_s_setprio(1);
#pragma unroll
        for (int mi = 0; mi < 4; mi++)
            acc[mi][0] = __builtin_amdgcn_mfma_f32_16x16x32_bf16(aF[mi], bF0, acc[mi][0], 0, 0, 0);
        __builtin_amdgcn_s_setprio(0);
        __builtin_amdgcn_s_barrier();

        // ---------------- P2: bF1 (+ counted vmcnt, once per kt) ----------------
        {
            int row = wn + 16 + fr;
            bF1 = *(const short8*)&lB[cur][row * 32 + ((quad ^ ((row >> 1) & 3)) & 3) * 8];
        }
        if (kt + 2 < 16) stageB(nx2, kt + 2);
        if (kt < 14)       asm volatile("s_waitcnt vmcnt(2) lgkmcnt(0)" ::: "memory");
        else if (kt == 14) asm volatile("s_waitcnt vmcnt(0) lgkmcnt(0)" ::: "memory");
        else               asm volatile("s_waitcnt lgkmcnt(0)" ::: "memory");
        __builtin_amdgcn_s_setprio(1);
#pragma unroll
        for (int mi = 0; mi < 4; mi++)
            acc[mi][1] = __builtin_amdgcn_mfma_f32_16x16x32_bf16(aF[mi], bF1, acc[mi][1], 0, 0, 0);
        __builtin_amdgcn_s_setprio(0);
        __builtin_amdgcn_s_barrier();

        cur += 1; if (cur >= 3) cur -= 3;
    }

    // EPI3: hoist per-row sigmoid
    float sgv[4][4];
    if (EPI == 3) {
#pragma unroll
        for (int mi = 0; mi < 4; mi++)
#pragma unroll
            for (int r = 0; r < 4; r++) {
                long row = m0 + wm + mi * 16 + quad * 4 + r;
                sgv[mi][r] = fsig(p.gate_pre[row * 8 + z] + bf2f(p.bgate[z]));
            }
    }

    // Epilogue: D row = quad*4+reg, col = lane&15
#pragma unroll
    for (int mi = 0; mi < 4; mi++) {
#pragma unroll
        for (int ni = 0; ni < 2; ni++) {
            const int mg = m0 + wm + mi * 16 + quad * 4;
            const int ng = n0 + wn + ni * 16 + fr;
#pragma unroll
            for (int r = 0; r < 4; r++) {
                float v = acc[mi][ni][r];
                const long row = mg + r;
                if (EPI == 1) {        // tanh(acc+add+bias) -> bf16   [link->fhs]
                    float ad = bf2f(p.add[z * p.addOff + row * p.ldadd + ng]);
                    v = ftanh(v + ad + bf2f(p.bias[p.biasOff[z] + ng]));
                    ((u16*)p.C)[p.cOff[z] + row * p.ldc + ng] = f2bf(v);
                } else if (EPI == 3) { // sig(gate)*tanh(acc+bias)     [upd]
                    v = ftanh(v + bf2f(p.bias[p.biasOff[z] + ng])) * sgv[mi][r];
                    ((u16*)p.C)[p.cOff[z] + row * p.ldc + ng] = f2bf(v);
                } else if (EPI == 6) { // (acc+bias) -> bf16            [cin]
                    v = v + bf2f(p.bias[p.biasOff[z] + ng]);
                    ((u16*)p.C)[p.cOff[z] + row * p.ldc + ng] = f2bf(v);
                } else {               // EPI 7: tanh(acc+add) -> bf16  [f0]
                    float ad = bf2f(p.add[row * p.ldadd + ng]);
                    v = ftanh(v + ad);
                    ((u16*)p.C)[row * p.ldc + ng] = f2bf(v);
                }
            }
        }
    }
}

// ---------------------------------------------------------------------------
// Fused GRU-GEMM — R9-verified 3-phase fine-interleaved schedule (52 us,
// 496 TF). 128x128 block, 8 waves (2Mx4N, 512 thr), 1 block/CU, 3-buf W +
// 2-buf A (88 KB), counted vmcnt never 0 in loop, setprio around MFMA.
// FROZEN — do not touch without within-probe A/B.
// ---------------------------------------------------------------------------
struct GGP {
    const u16* fhs_in;    // [b][s][1024]  (feats | hs_b)
    u16* fhs_out;         // write hs_b' at [b][s][512+w]
    const u16* Wcat;      // [s][1536][1024]
    const u16* b_ih;      // [s][1536]
    const u16* b_hh;      // [s][1536]
    u16* prism;           // [b][s][512]
    float* gate_pre;      // [b][8]  (atomicAdd, pre-zeroed)
    const u16* Wg;        // [s][512]
    const u16* phase;     // [s][512]
    const u16* pgain;     // [s][512]
};

__global__ __launch_bounds__(512, 2) void grug_k(GGP p) {
    __shared__ __align__(16) u16 sA[2][128 * 32];       // 16 KB
    __shared__ __align__(16) u16 sW[3][3][128 * 32];    // 72 KB
    const int t    = threadIdx.x;
    const int lane = t & 63;
    const int wv   = t >> 6;           // 0..7
    // XCD-group swizzle (grid (32,8)): s = wgid%8 -> one s per XCD.
    const int wgid = blockIdx.x + (blockIdx.y << 5);
    const int s    = wgid & 7;
    const int idx  = wgid >> 3;        // 0..31
    const int w0   = (idx & 3) * 128;
    const int m0   = (idx >> 2) * 128;
    const int fr   = lane & 15;
    const int quad = lane >> 4;
    const int wm   = (wv & 1) * 64;    // wave's m-range (64 rows of 128)
    const int wn   = (wv >> 1) * 32;   // wave's n-range (32 cols of 128)

    const u16* Ab = p.fhs_in + (long)m0 * 8192 + (long)s * 1024;
    const u16* Wb = p.Wcat + (long)s * 1536 * 1024;

    f32x4 acc[4][4][2];   // [q: r,z,inn,hn][mi 0..3][ni 0..1]
#pragma unroll
    for (int q = 0; q < 4; q++)
#pragma unroll
        for (int mi = 0; mi < 4; mi++)
#pragma unroll
            for (int ni = 0; ni < 2; ni++) acc[q][mi][ni] = (f32x4){0.f,0.f,0.f,0.f};

    const int arow = t >> 2, ac4 = t & 3, asrc = ac4 ^ ((arow >> 1) & 3);

    auto stageA = [&](int buf, int kt) {
        gload_lds16(Ab + (long)arow * 8192 + kt * 32 + asrc * 8, &sA[buf][t * 8]);
    };
    auto stageWq = [&](int buf, int kt, int q) {
        long g = (long)(q * 512 + w0 + arow);
        gload_lds16(Wb + g * 1024 + kt * 32 + asrc * 8, &sW[buf][q][t * 8]);
    };

    // Prologue: A(0)+W(0) must land; W(1) stays in flight.  queue: A0,W0x3,W1x3
    stageA(0, 0);
    stageWq(0, 0, 0); stageWq(0, 0, 1); stageWq(0, 0, 2);
    stageWq(1, 1, 0); stageWq(1, 1, 1); stageWq(1, 1, 2);
    asm volatile("s_waitcnt vmcnt(3)" ::: "memory");
    __builtin_amdgcn_s_barrier();

    int aCur = 0, wCur = 0;
    for (int kt = 0; kt < 32; ++kt) {
        const int aNxt = aCur ^ 1;
        int wNx2 = wCur + 2; if (wNx2 >= 3) wNx2 -= 3;
        short8 aF[4], bF0[2], bF1[2], bF2[2];

        // ---------------- P1: aF + bF0 ----------------
#pragma unroll
        for (int mi = 0; mi < 4; mi++) {
            int row = wm + mi * 16 + fr;
            aF[mi] = *(const short8*)&sA[aCur][row * 32 + ((quad ^ ((row >> 1) & 3)) & 3) * 8];
        }
#pragma unroll
        for (int ni = 0; ni < 2; ni++) {
            int row = wn + ni * 16 + fr;
            bF0[ni] = *(const short8*)&sW[wCur][0][row * 32 + ((quad ^ ((row >> 1) & 3)) & 3) * 8];
        }
        if (kt + 1 < 32) stageA(aNxt, kt + 1);
        if (kt + 2 < 32) stageWq(wNx2, kt + 2, 0);
        __builtin_amdgcn_s_barrier();
        asm volatile("s_waitcnt lgkmcnt(0)" ::: "memory");
        __builtin_amdgcn_s_setprio(1);
#pragma unroll
        for (int mi = 0; mi < 4; mi++)
#pragma unroll
            for (int ni = 0; ni < 2; ni++)
                acc[0][mi][ni] = __builtin_amdgcn_mfma_f32_16x16x32_bf16(aF[mi], bF0[ni], acc[0][mi][ni], 0, 0, 0);
        __builtin_amdgcn_s_setprio(0);
        __builtin_amdgcn_s_barrier();

        // ---------------- P2: bF1 ----------------
#pragma unroll
        for (int ni = 0; ni < 2; ni++) {
            int row = wn + ni * 16 + fr;
            bF1[ni] = *(const short8*)&sW[wCur][1][row * 32 + ((quad ^ ((row >> 1) & 3)) & 3) * 8];
        }
        if (kt + 2 < 32) stageWq(wNx2, kt + 2, 1);
        __builtin_amdgcn_s_barrier();
        asm volatile("s_waitcnt lgkmcnt(0)" ::: "memory");
        __builtin_amdgcn_s_setprio(1);
#pragma unroll
        for (int mi = 0; mi < 4; mi++)
#pragma unroll
            for (int ni = 0; ni < 2; ni++)
                acc[1][mi][ni] = __builtin_amdgcn_mfma_f32_16x16x32_bf16(aF[mi], bF1[ni], acc[1][mi][ni], 0, 0, 0);
        __builtin_amdgcn_s_setprio(0);
        __builtin_amdgcn_s_barrier();

        // ---------------- P3: bF2 (+ counted vmcnt, once per kt) ----------------
#pragma unroll
        for (int ni = 0; ni < 2; ni++) {
            int row = wn + ni * 16 + fr;
            bF2[ni] = *(const short8*)&sW[wCur][2][row * 32 + ((quad ^ ((row >> 1) & 3)) & 3) * 8];
        }
        if (kt + 2 < 32) stageWq(wNx2, kt + 2, 2);
        if (kt < 30)       asm volatile("s_waitcnt vmcnt(3) lgkmcnt(0)" ::: "memory");
        else if (kt == 30) asm volatile("s_waitcnt vmcnt(0) lgkmcnt(0)" ::: "memory");
        else               asm volatile("s_waitcnt lgkmcnt(0)" ::: "memory");
        __builtin_amdgcn_s_setprio(1);
        if (kt < 16) {
#pragma unroll
            for (int mi = 0; mi < 4; mi++)
#pragma unroll
                for (int ni = 0; ni < 2; ni++)
                    acc[2][mi][ni] = __builtin_amdgcn_mfma_f32_16x16x32_bf16(aF[mi], bF2[ni], acc[2][mi][ni], 0, 0, 0);
        } else {
#pragma unroll
            for (int mi = 0; mi < 4; mi++)
#pragma unroll
                for (int ni = 0; ni < 2; ni++)
                    acc[3][mi][ni] = __builtin_amdgcn_mfma_f32_16x16x32_bf16(aF[mi], bF2[ni], acc[3][mi][ni], 0, 0, 0);
        }
        __builtin_amdgcn_s_setprio(0);
        __builtin_amdgcn_s_barrier();

        aCur = aNxt;
        wCur += 1; if (wCur >= 3) wCur -= 3;
    }

    // Epilogue: ni-outer so the 9 per-column params load once per column.
    const u16* bih = p.b_ih + (long)s * 1536;
    const u16* bhh = p.b_hh + (long)s * 1536;
    float gp[4][4];
#pragma unroll
    for (int mi = 0; mi < 4; mi++)
#pragma unroll
        for (int r = 0; r < 4; r++) gp[mi][r] = 0.f;

#pragma unroll
    for (int ni = 0; ni < 2; ni++) {
        const int col = w0 + wn + ni * 16 + fr;          // w in [0,512)
        const float br  = bf2f(bih[col])        + bf2f(bhh[col]);
        const float bz  = bf2f(bih[512 + col])  + bf2f(bhh[512 + col]);
        const float bin = bf2f(bih[1024 + col]);
        const float bhn = bf2f(bhh[1024 + col]);
        const float ph  = bf2f(p.phase[s * 512 + col]);
        const float gain = fsoftplus(bf2f(p.pgain[s * 512 + col]));
        const float wg  = bf2f(p.Wg[s * 512 + col]);
#pragma unroll
        for (int mi = 0; mi < 4; mi++) {
#pragma unroll
            for (int r = 0; r < 4; r++) {
                const long b = m0 + wm + mi * 16 + quad * 4 + r;
                float rv = fsig(acc[0][mi][ni][r] + br);
                float zv = fsig(acc[1][mi][ni][r] + bz);
                float nv = ftanh(acc[2][mi][ni][r] + bin + rv * (acc[3][mi][ni][r] + bhn));
                float hold = bf2f(p.fhs_in[b * 8192 + s * 1024 + 512 + col]);
                float hv = (1.f - zv) * nv + zv * hold;
                p.fhs_out[b * 8192 + s * 1024 + 512 + col] = f2bf(hv);
                float c = __cosf(hv + ph);
                p.prism[b * 4096 + s * 512 + col] = f2bf(c * c * gain);
                gp[mi][r] += wg * hv;
            }
        }
    }
    // reduce over fr (16 lanes within quad), then one atomic per row
#pragma unroll
    for (int m = 1; m < 16; m <<= 1)
#pragma unroll
        for (int mi = 0; mi < 4; mi++)
#pragma unroll
            for (int r = 0; r < 4; r++) gp[mi][r] += __shfl_xor(gp[mi][r], m, 64);
    if (fr == 0) {
#pragma unroll
        for (int mi = 0; mi < 4; mi++)
#pragma unroll
            for (int r = 0; r < 4; r++) {
                long b = m0 + wm + mi * 16 + quad * 4 + r;
                atomicAdd(&p.gate_pre[b * 8 + s], gp[mi][r]);
            }
    }
}

// ---------------------------------------------------------------------------
// Encode: masked mean / masked max / last token -> cat [B,1536]
// ---------------------------------------------------------------------------
__global__ __launch_bounds__(256) void encode_k(const int* __restrict__ x,
                                                const u16* __restrict__ embed,
                                                u16* __restrict__ cat) {
    __shared__ int toks[128];
    __shared__ int cnt_s;
    const int b = blockIdx.x, t = threadIdx.x;
    if (t < 128) toks[t] = x[b * 128 + t];
    __syncthreads();
    if (t == 0) {
        int c = 0;
        for (int l = 0; l < 128; l++) c += (toks[l] != 0);
        cnt_s = c;
    }
    __syncthreads();
    const int cnt = cnt_s;
    const int lastTok = toks[cnt > 0 ? cnt - 1 : 0];
    for (int w = t; w < 512; w += 256) {
        float sum = 0.f, mx = -10000.f;
        for (int l = 0; l < 128; l++) {
            int tok = toks[l];
            if (tok != 0) {
                float e = bf2f(embed[tok * 512 + w]);
                sum += e;
                mx = fmaxf(mx, e);
            }
        }
        float mean = sum / (float)(cnt > 0 ? cnt : 1);
        float last = bf2f(embed[lastTok * 512 + w]);
        cat[(long)b * 1536 + w]        = f2bf(mean);
        cat[(long)b * 1536 + 512 + w]  = f2bf(mx);
        cat[(long)b * 1536 + 1024 + w] = f2bf(last);
    }
}

// ---------------------------------------------------------------------------
// delta = sum_s upd / sqrt(S);  h = tanh(h*decay + delta); h_b = bf16(h)
// Also zeroes gate_pre for the NEXT step's grug (replaces 12 memset
// dispatches; ordering: grug fills -> upd-gemm reads -> hupd zeroes).
// ---------------------------------------------------------------------------
__global__ __launch_bounds__(256) void hupd_k(const u16* __restrict__ upd,
                                              float* __restrict__ h,
                                              u16* __restrict__ h_b,
                                              const u16* __restrict__ decay_p,
                                              float* __restrict__ gate_pre) {
    const int idx = blockIdx.x * 256 + threadIdx.x;
    if (idx < 8192) gate_pre[idx] = 0.f;
    const int b = idx >> 9, w = idx & 511;
    const long base = (long)b * 4096 + w;
    float dsum = 0.f;
#pragma unroll
    for (int s = 0; s < 8; s++) dsum += bf2f(upd[base + s * 512]);
    const float decay = fsig(bf2f(decay_p[0]));
    const float hv = ftanh(h[idx] * decay + dsum * 0.35355339059327373f);
    h[idx] = hv;
    h_b[idx] = f2bf(hv);
}

// ---------------------------------------------------------------------------
// Final head; output dtype follows detected input dtype.
// ---------------------------------------------------------------------------
__global__ __launch_bounds__(64) void out_k(const float* __restrict__ h,
                                            const u16* __restrict__ Wout,
                                            const u16* __restrict__ bout,
                                            void* __restrict__ out,
                                            const int* __restrict__ flag) {
    const int b = blockIdx.x, lane = threadIdx.x;
    const int isbf = *flag;
    for (int j = 0; j < 10; j++) {
        float p = 0.f;
#pragma unroll
        for (int k = 0; k < 8; k++) {
            int w = lane + k * 64;
            p += h[(long)b * 512 + w] * bf2f(Wout[j * 512 + w]);
        }
#pragma unroll
        for (int off = 32; off; off >>= 1) p += __shfl_down(p, off, 64);
        if (lane == 0) {
            float val = p + bf2f(bout[j]);
            if (isbf) ((u16*)out)[b * 10 + j] = f2bf(val);
            else      ((float*)out)[b * 10 + j] = val;
        }
    }
}

// ---------------------------------------------------------------------------
extern "C" void kernel_launch(void* const* d_in, const int* in_sizes, int n_in,
                              void* d_out, int out_size, void* d_ws, size_t ws_size,
                              hipStream_t stream) {
    (void)n_in; (void)out_size; (void)ws_size;
    const int* x = (const int*)d_in[0];

    char* pp = (char*)d_ws;
    auto carve = [&](size_t n) { char* r = pp; pp += (n + 255) & ~(size_t)255; return (void*)r; };

    // canonical bf16 parameter block (~44 MB)
    CT ct;
    size_t ctot = 0;
    for (int i = 0; i < 20; i++) {
        ct.src[i] = d_in[i + 1];
        ct.n[i]   = in_sizes[i + 1];
        ct.off[i] = (int)ctot;
        ctot += ((size_t)in_sizes[i + 1] + 15) & ~(size_t)15;
    }
    u16* canon = (u16*)carve(ctot * 2);
    const u16* embed  = canon + ct.off[0];
    const u16* W_mix  = canon + ct.off[1];
    const u16* b_mix  = canon + ct.off[2];
    const u16* W_in   = canon + ct.off[3];
    const u16* b_in   = canon + ct.off[4];
    const u16* W_link = canon + ct.off[5];
    const u16* b_link = canon + ct.off[6];
    const u16* W_ih   = canon + ct.off[7];
    const u16* b_ih   = canon + ct.off[8];
    const u16* W_hh   = canon + ct.off[9];
    const u16* b_hh   = canon + ct.off[10];
    const u16* W_gate = canon + ct.off[11];
    const u16* b_gate = canon + ct.off[12];
    const u16* phase  = canon + ct.off[13];
    const u16* pgain  = canon + ct.off[14];
    const u16* W_delta= canon + ct.off[15];
    const u16* b_delta= canon + ct.off[16];
    const u16* decayp = canon + ct.off[17];
    const u16* W_out  = canon + ct.off[18];
    const u16* b_out  = canon + ct.off[19];

    int*   flag   = (int*)  carve(256);
    u16*   Wcat   = (u16*)  carve((size_t)8 * 1536 * 1024 * 2);  // 25 MB
    u16*   cat    = (u16*)  carve((size_t)1024 * 1536 * 2);
    u16*   h_b    = (u16*)  carve((size_t)1024 * 512 * 2);
    u16*   summ_b = (u16*)  carve((size_t)1024 * 512 * 2);
    float* h      = (float*)carve((size_t)1024 * 512 * 4);
    u16*   cin    = (u16*)  carve((size_t)1024 * 4096 * 2);
    u16*   f0     = (u16*)  carve((size_t)1024 * 4096 * 2);
    u16*   fhs0   = (u16*)  carve((size_t)1024 * 8192 * 2);      // 16 MB
    u16*   fhs1   = (u16*)  carve((size_t)1024 * 8192 * 2);      // 16 MB
    u16*   prism  = (u16*)  carve((size_t)1024 * 4096 * 2);
    u16*   upd    = (u16*)  carve((size_t)1024 * 4096 * 2);
    float* gate_pre = (float*)carve((size_t)1024 * 8 * 4);

    (void)hipMemsetAsync(fhs0, 0, (size_t)1024 * 8192 * 2, stream);
    (void)hipMemsetAsync(fhs1, 0, (size_t)1024 * 8192 * 2, stream);
    (void)hipMemsetAsync(gate_pre, 0, (size_t)1024 * 8 * 4, stream);

    detect_k<<<dim3(1), dim3(256), 0, stream>>>((const u16*)d_in[1], flag);
    conv_k<<<dim3(1024), dim3(256), 0, stream>>>(ct, canon, flag);
    pack_k<<<dim3(3072), dim3(256), 0, stream>>>(W_ih, W_hh, Wcat);
    encode_k<<<dim3(1024), dim3(256), 0, stream>>>(x, embed, cat);

    {   // summary = tanh(cat @ W_mix^T + b_mix) -> h_b, summ_b, h
        GP p{}; p.A = cat; p.lda = 1536; p.Bw = W_mix; p.ldb = 1536;
        p.bias = b_mix; p.C = h_b; p.ldc = 512; p.C2 = h; p.C3 = summ_b;
        p.K = 1536; p.nt = 4;
        gemm_k<4, 64, 0><<<dim3(4, 16, 1), dim3(256), 0, stream>>>(p);
    }
    {   // cin = summary @ W_in[:, :, 512:]^T + b_in   [gemm8]
        GP p{}; p.A = summ_b; p.lda = 512; p.Bw = W_in + 512; p.ldb = 1024;
        p.bias = b_in; p.C = cin; p.ldc = 4096; p.K = 512; p.nt = 32;
        gemm8_k<6><<<dim3(32, 8, 1), dim3(512), 0, stream>>>(p);
    }

    for (int step = 0; step < 12; ++step) {
        u16* fhs_cur = (step & 1) ? fhs1 : fhs0;
        u16* fhs_nxt = (step & 1) ? fhs0 : fhs1;
        {   // f0 = tanh(h @ W_in[:, :, :512]^T + cin)   [gemm8]
            GP p{}; p.A = h_b; p.lda = 512; p.Bw = W_in; p.ldb = 1024;
            p.add = cin; p.ldadd = 4096; p.C = f0; p.ldc = 4096;
            p.K = 512; p.nt = 32;
            gemm8_k<7><<<dim3(32, 8, 1), dim3(512), 0, stream>>>(p);
        }
        {   // feats = tanh(f0 + prev @ W_link^T + b_link) -> fhs_cur[:, s, 0:512]
            GP p{}; p.A = f0; p.lda = 4096;
            for (int s = 0; s < 8; s++) p.aOff[s] = (long)((s + 7) & 7) * 512;
            p.Bw = W_link; p.ldb = 512;
            for (int s = 0; s < 8; s++) p.bwOff[s] = (long)s * 512 * 512;
            p.bias = b_link;
            for (int s = 0; s < 8; s++) p.biasOff[s] = (long)s * 512;
            p.add = f0; p.ldadd = 4096; p.addOff = 512;
            p.C = fhs_cur; p.ldc = 8192;
            for (int s = 0; s < 8; s++) p.cOff[s] = (long)s * 1024;
            p.K = 512; p.nt = 4;
            gemm8_k<1><<<dim3(32, 8, 1), dim3(512), 0, stream>>>(p);
        }
        {   // fused GRU-GEMM (R9-frozen 3-phase)
            GGP g{};
            g.fhs_in = fhs_cur; g.fhs_out = fhs_nxt; g.Wcat = Wcat;
            g.b_ih = b_ih; g.b_hh = b_hh; g.prism = prism; g.gate_pre = gate_pre;
            g.Wg = W_gate; g.phase = phase; g.pgain = pgain;
            grug_k<<<dim3(32, 8, 1), dim3(512), 0, stream>>>(g);
        }
        {   // upd = sig(gate)*tanh(prism @ W_delta^T + b_delta) -> bf16
            GP p{}; p.A = prism; p.lda = 4096;
            for (int s = 0; s < 8; s++) p.aOff[s] = (long)s * 512;
            p.Bw = W_delta; p.ldb = 512;
            for (int s = 0; s < 8; s++) p.bwOff[s] = (long)s * 512 * 512;
            p.bias = b_delta;
            for (int s = 0; s < 8; s++) p.biasOff[s] = (long)s * 512;
            p.gate_pre = gate_pre; p.bgate = b_gate;
            p.C = upd; p.ldc = 4096;
            for (int s = 0; s < 8; s++) p.cOff[s] = (long)s * 512;
            p.K = 512; p.nt = 4;
            gemm8_k<3><<<dim3(32, 8, 1), dim3(512), 0, stream>>>(p);
        }
        hupd_k<<<dim3(2048), dim3(256), 0, stream>>>(upd, h, h_b, decayp, gate_pre);
    }

    out_k<<<dim3(1024), dim3(64), 0, stream>>>(h, W_out, b_out, d_out, flag);
}

// Round 11
// 1488.466 us; speedup vs baseline: 1.0459x; 1.0459x over previous
//
#include <hip/hip_runtime.h>
#include <hip/hip_bf16.h>

// B=1024, L=128, W=512, S=8, STEPS=12, VOCAB=32, NLAB=10

typedef unsigned short u16;
typedef __attribute__((ext_vector_type(8))) short short8;   // 8 x bf16
typedef __attribute__((ext_vector_type(4))) float f32x4;

__device__ __forceinline__ float bf2f(u16 v) {
    union { unsigned int u; float f; } x; x.u = ((unsigned int)v) << 16; return x.f;
}
__device__ __forceinline__ u16 f2bf(float f) {
    union { float f; unsigned int u; } x; x.f = f;
    unsigned int u = x.u;
    return (u16)((u + 0x7FFFu + ((u >> 16) & 1u)) >> 16);   // RNE
}
// Fast transcendentals: v_exp/v_log/v_cos/v_rcp HW ops (~1e-6 err << bf16 eps)
__device__ __forceinline__ float fsig(float v) {
    return __builtin_amdgcn_rcpf(1.f + __expf(-v));
}
__device__ __forceinline__ float ftanh(float v) {
    return 1.f - 2.f * __builtin_amdgcn_rcpf(__expf(2.f * v) + 1.f);
}
__device__ __forceinline__ float fsoftplus(float v) {
    return (v > 20.f) ? v : __logf(1.f + __expf(v));
}

union U4 { ushort4 v; u16 e[4]; };

// Async global->LDS, 16B/lane. LDS dest = wave-uniform base + lane*16.
__device__ __forceinline__ void gload_lds16(const u16* g, u16* l) {
    __builtin_amdgcn_global_load_lds(
        (const __attribute__((address_space(1))) unsigned int*)g,
        (__attribute__((address_space(3))) unsigned int*)l, 16, 0, 0);
}

// ---------------------------------------------------------------------------
// Input-dtype detection (bf16 vs f32 inputs).
// ---------------------------------------------------------------------------
__device__ __forceinline__ int sane16(u16 u) {
    if ((u & 0x7FFF) == 0) return 1;
    int e = (u >> 7) & 0xFF;
    return (e >= 0x33 && e <= 0x43) ? 1 : 0;
}
__global__ __launch_bounds__(256) void detect_k(const u16* __restrict__ raw,
                                                int* __restrict__ flag) {
    const int t = threadIdx.x;
    int c = sane16(raw[1024 + t * 2]) + sane16(raw[1024 + t * 2 + 1]);
#pragma unroll
    for (int off = 32; off; off >>= 1) c += __shfl_down(c, off, 64);
    __shared__ int red[4];
    if ((t & 63) == 0) red[t >> 6] = c;
    __syncthreads();
    if (t == 0) *flag = (red[0] + red[1] + red[2] + red[3] >= 448) ? 1 : 0;
}

// ---------------------------------------------------------------------------
// Canonicalize float tensors to bf16, vectorized.
// ---------------------------------------------------------------------------
struct CT { const void* src[20]; int n[20]; int off[20]; };
__global__ __launch_bounds__(256) void conv_k(CT ct, u16* __restrict__ dstBase,
                                              const int* __restrict__ flag) {
    const int isbf = *flag;
    const int gid = blockIdx.x * 256 + threadIdx.x;
    const int stride = gridDim.x * 256;
    for (int tn = 0; tn < 20; ++tn) {
        const int n = ct.n[tn];
        const int n4 = n >> 2;
        u16* dst = dstBase + ct.off[tn];
        if (!isbf) {
            const float* s = (const float*)ct.src[tn];
            for (int i = gid; i < n4; i += stride) {
                f32x4 v = *(const f32x4*)(s + i * 4);
                *(ushort4*)(dst + i * 4) =
                    make_ushort4(f2bf(v[0]), f2bf(v[1]), f2bf(v[2]), f2bf(v[3]));
            }
            if (gid < (n & 3)) { int i = n4 * 4 + gid; dst[i] = f2bf(s[i]); }
        } else {
            const u16* s = (const u16*)ct.src[tn];
            for (int i = gid; i < n4; i += stride)
                *(ushort4*)(dst + i * 4) = *(const ushort4*)(s + i * 4);
            if (gid < (n & 3)) { int i = n4 * 4 + gid; dst[i] = s[i]; }
        }
    }
}

// ---------------------------------------------------------------------------
// Pack Wcat[s][g][0:512]=W_ih[s][g][:], [512:1024]=W_hh[s][g][:]  (one-time)
// ---------------------------------------------------------------------------
__global__ __launch_bounds__(256) void pack_k(const u16* __restrict__ Wih,
                                              const u16* __restrict__ Whh,
                                              u16* __restrict__ Wcat) {
    long i = ((long)blockIdx.x * 256 + threadIdx.x) * 8;   // over 8*1536*512
    if (i >= 8L * 1536 * 512) return;
    long sg = i >> 9;
    long k  = i & 511;
    *(short8*)(Wcat + sg * 1024 + k)       = *(const short8*)(Wih + i);
    *(short8*)(Wcat + sg * 1024 + 512 + k) = *(const short8*)(Whh + i);
}

// ---------------------------------------------------------------------------
// Batched GEMM params (shared by gemm_k and gemm8_k).
// ---------------------------------------------------------------------------
struct GP {
    const u16* A;  long lda; long aOff[8];
    const u16* Bw; long ldb; long bwOff[8];
    const u16* bias; long biasOff[8];
    const u16* add; long ldadd; long addOff;
    const float* gate_pre;                      // EPI 3
    const u16* bgate;                           // EPI 3
    void* C; long ldc; long cOff[8];
    float* C2;                                  // EPI 4
    u16* C3;                                    // EPI 4
    int K; int nt;
};

// ---------------------------------------------------------------------------
// Legacy batched GEMM (R3-proven 2-buffer), used only for the K=1536
// prologue mix (EPI 4, one dispatch).
// ---------------------------------------------------------------------------
template<int EPI, int MT, int SWZ>
__global__ __launch_bounds__(256) void gemm_k(GP p) {
    constexpr int MW   = MT / 32;   // m-tiles per wave
    constexpr int AITS = MT / 32;   // A staging iterations
    __shared__ __align__(16) u16 lA[2][MT * 64];
    __shared__ __align__(16) u16 lB[2][128 * 64];
    const int t    = threadIdx.x;
    const int lane = t & 63;
    const int wv   = t >> 6;
    int bx = blockIdx.x, byy = blockIdx.y;
    if (SWZ) {
        int wgid = bx + (byy << 5);
        bx  = ((wgid & 7) << 2) + ((wgid >> 3) & 3);
        byy = wgid >> 5;
    }
    const int z    = bx / p.nt;
    const int n0   = (bx - z * p.nt) * 128;
    const int m0   = byy * MT;

    const u16* Ab = p.A + p.aOff[z] + (long)m0 * p.lda;
    const u16* Bb = p.Bw + p.bwOff[z] + (long)n0 * p.ldb;

    f32x4 acc[MW][4];
#pragma unroll
    for (int i = 0; i < MW; i++)
#pragma unroll
        for (int j = 0; j < 4; j++) acc[i][j] = (f32x4){0.f, 0.f, 0.f, 0.f};

    const int wm   = (wv & 1) * (MT / 2);
    const int wn   = (wv >> 1) * 64;
    const int fr   = lane & 15;
    const int quad = lane >> 4;

    auto stage = [&](int buf, long kb) {
#pragma unroll
        for (int it = 0; it < AITS; ++it) {
            int flat = it * 256 + t, row = flat >> 3, src = (flat & 7) ^ (row & 7);
            gload_lds16(Ab + (long)row * p.lda + kb + src * 8, &lA[buf][flat * 8]);
        }
#pragma unroll
        for (int it = 0; it < 4; ++it) {
            int flat = it * 256 + t, row = flat >> 3, src = (flat & 7) ^ (row & 7);
            gload_lds16(Bb + (long)row * p.ldb + kb + src * 8, &lB[buf][flat * 8]);
        }
    };
    auto inner = [&](int cur) {
#pragma unroll
        for (int kk = 0; kk < 2; ++kk) {
            const int q = kk * 4 + quad;
            short8 aF[MW], bF[4];
#pragma unroll
            for (int mi = 0; mi < MW; mi++) {
                int row = wm + mi * 16 + fr;
                aF[mi] = *(const short8*)&lA[cur][row * 64 + (q ^ (row & 7)) * 8];
            }
#pragma unroll
            for (int ni = 0; ni < 4; ni++) {
                int row = wn + ni * 16 + fr;
                bF[ni] = *(const short8*)&lB[cur][row * 64 + (q ^ (row & 7)) * 8];
            }
#pragma unroll
            for (int mi = 0; mi < MW; mi++)
#pragma unroll
                for (int ni = 0; ni < 4; ni++)
                    acc[mi][ni] = __builtin_amdgcn_mfma_f32_16x16x32_bf16(
                        aF[mi], bF[ni], acc[mi][ni], 0, 0, 0);
        }
    };

    const int nk = p.K >> 6;
    stage(0, 0);
    __syncthreads();
    for (int kt = 0; kt < nk; ++kt) {
        const int cur = kt & 1, nxt = cur ^ 1;
        if (kt + 1 < nk) stage(nxt, (long)(kt + 1) * 64);
        inner(cur);
        __syncthreads();
    }

    // Epilogue: D row = quad*4+reg, col = lane&15
#pragma unroll
    for (int mi = 0; mi < MW; mi++) {
#pragma unroll
        for (int ni = 0; ni < 4; ni++) {
            const int mg = m0 + wm + mi * 16 + quad * 4;
            const int ng = n0 + wn + ni * 16 + fr;
#pragma unroll
            for (int r = 0; r < 4; r++) {
                float v = acc[mi][ni][r];
                const long row = mg + r;
                if (EPI == 4) {        // encode mix: h_b, summ_b, h(f32)
                    v = ftanh(v + bf2f(p.bias[ng]));
                    u16 b = f2bf(v);
                    ((u16*)p.C)[row * 512 + ng] = b;
                    p.C3[row * 512 + ng] = b;
                    p.C2[row * 512 + ng] = v;
                }
            }
        }
    }
}

// ---------------------------------------------------------------------------
// gemm8_k — R10 widened: BK=64, nk=8, 2 phases/kt, each phase = one K=32
// slice with 6 ds_read_b128 + 8 MFMA + 2 stage-gloads — grug's PROVEN
// per-phase profile (R9: +10%). R10's thin 4-MFMA phases regressed (-9%);
// this halves barriers (64->32) and doubles MFMA per barrier.
// 128x128 block, 8 waves (2Mx4N, 512 thr), 1 block/CU (grid 256), 3-buffer
// A+B of 128x64 tiles (96 KB), 128B-row swizzle f(row)=row&7 (R0-proven).
//   P1 (k-slice 0, chunk q=quad):  ds aF0[4]+bF0[2]; issue stageA(kt+2);
//       bar; lgkmcnt(0); prio1; 8 MFMA; prio0; bar
//   P2 (k-slice 1, chunk q=4+quad): ds aF1[4]+bF1[2]; issue stageB(kt+2);
//       vmcnt(4)+lgkm [kt=6: vmcnt(0); kt=7: lgkm]; prio1; 8 MFMA; prio0; bar
// vmcnt ledger (4 gloads/thread/kt, order A,B): end-of-kt queue =
// A(kt+1)2,B(kt+1)2,A(kt+2)2,B(kt+2)2 = 8 -> vmcnt(4) lands tile kt+1,
// tile kt+2 flies across the barrier. WAR: buffer (kt+2)%3 was last read
// in kt-1's P2, closed by its lgkmcnt(0)+final barrier.
// Block mapping: zc=wgid&7 -> one weight slab per XCD (nt=4); bijective
// for nt=32. ct = zc*4 + ((wgid>>3)&3), m0=(wgid>>5)*128.
// ---------------------------------------------------------------------------
template<int EPI>
__global__ __launch_bounds__(512, 2) void gemm8_k(GP p) {
    __shared__ __align__(16) u16 lA[3][128 * 64];   // 48 KB
    __shared__ __align__(16) u16 lB[3][128 * 64];   // 48 KB
    const int t    = threadIdx.x;
    const int lane = t & 63;
    const int wv   = t >> 6;           // 0..7
    const int wgid = blockIdx.x + (blockIdx.y << 5);   // grid (32,8)
    const int zc   = wgid & 7;
    const int ct   = zc * 4 + ((wgid >> 3) & 3);       // col tile 0..31
    const int m0   = (wgid >> 5) * 128;
    const int z    = ct / p.nt;
    const int n0   = (ct - z * p.nt) * 128;
    const int fr   = lane & 15;
    const int quad = lane >> 4;
    const int wm   = (wv & 1) * 64;    // wave's m-range (64 rows of 128)
    const int wn   = (wv >> 1) * 32;   // wave's n-range (32 cols of 128)

    const u16* Ab = p.A + p.aOff[z] + (long)m0 * p.lda;
    const u16* Bb = p.Bw + p.bwOff[z] + (long)n0 * p.ldb;

    f32x4 acc[4][2];
#pragma unroll
    for (int mi = 0; mi < 4; mi++)
#pragma unroll
        for (int ni = 0; ni < 2; ni++) acc[mi][ni] = (f32x4){0.f, 0.f, 0.f, 0.f};

    // Staging (512 threads, 2 it): 128x64 tile = 1024 chunks of 8 u16.
    // LDS[row][c8] = Global[row][c8 ^ (row&7)]  (128B-row XOR swizzle).
    auto stageA = [&](int buf, int kt) {
#pragma unroll
        for (int it = 0; it < 2; ++it) {
            int flat = it * 512 + t, row = flat >> 3, src = (flat & 7) ^ (row & 7);
            gload_lds16(Ab + (long)row * p.lda + kt * 64 + src * 8, &lA[buf][flat * 8]);
        }
    };
    auto stageB = [&](int buf, int kt) {
#pragma unroll
        for (int it = 0; it < 2; ++it) {
            int flat = it * 512 + t, row = flat >> 3, src = (flat & 7) ^ (row & 7);
            gload_lds16(Bb + (long)row * p.ldb + kt * 64 + src * 8, &lB[buf][flat * 8]);
        }
    };

    // Prologue: tiles 0,1 in flight (8 gloads); wait for tile 0 (oldest 4).
    stageA(0, 0); stageB(0, 0); stageA(1, 1); stageB(1, 1);
    asm volatile("s_waitcnt vmcnt(4)" ::: "memory");
    __builtin_amdgcn_s_barrier();

    int cur = 0;
    for (int kt = 0; kt < 8; ++kt) {
        int nx2 = cur + 2; if (nx2 >= 3) nx2 -= 3;
        short8 aF[4], bF[2];

        // ---------------- P1: k-slice 0 (chunk q = quad) ----------------
        {
            const int q = quad;
#pragma unroll
            for (int mi = 0; mi < 4; mi++) {
                int row = wm + mi * 16 + fr;
                aF[mi] = *(const short8*)&lA[cur][row * 64 + (q ^ (row & 7)) * 8];
            }
#pragma unroll
            for (int ni = 0; ni < 2; ni++) {
                int row = wn + ni * 16 + fr;
                bF[ni] = *(const short8*)&lB[cur][row * 64 + (q ^ (row & 7)) * 8];
            }
        }
        if (kt + 2 < 8) stageA(nx2, kt + 2);
        __builtin_amdgcn_s_barrier();
        asm volatile("s_waitcnt lgkmcnt(0)" ::: "memory");
        __builtin_amdgcn_s_setprio(1);
#pragma unroll
        for (int mi = 0; mi < 4; mi++)
#pragma unroll
            for (int ni = 0; ni < 2; ni++)
                acc[mi][ni] = __builtin_amdgcn_mfma_f32_16x16x32_bf16(aF[mi], bF[ni], acc[mi][ni], 0, 0, 0);
        __builtin_amdgcn_s_setprio(0);
        __builtin_amdgcn_s_barrier();

        // ---------------- P2: k-slice 1 (chunk q = 4+quad) ----------------
        {
            const int q = 4 + quad;
#pragma unroll
            for (int mi = 0; mi < 4; mi++) {
                int row = wm + mi * 16 + fr;
                aF[mi] = *(const short8*)&lA[cur][row * 64 + (q ^ (row & 7)) * 8];
            }
#pragma unroll
            for (int ni = 0; ni < 2; ni++) {
                int row = wn + ni * 16 + fr;
                bF[ni] = *(const short8*)&lB[cur][row * 64 + (q ^ (row & 7)) * 8];
            }
        }
        if (kt + 2 < 8) stageB(nx2, kt + 2);
        if (kt < 6)       asm volatile("s_waitcnt vmcnt(4) lgkmcnt(0)" ::: "memory");
        else if (kt == 6) asm volatile("s_waitcnt vmcnt(0) lgkmcnt(0)" ::: "memory");
        else              asm volatile("s_waitcnt lgkmcnt(0)" ::: "memory");
        __builtin_amdgcn_s_setprio(1);
#pragma unroll
        for (int mi = 0; mi < 4; mi++)
#pragma unroll
            for (int ni = 0; ni < 2; ni++)
                acc[mi][ni] = __builtin_amdgcn_mfma_f32_16x16x32_bf16(aF[mi], bF[ni], acc[mi][ni], 0, 0, 0);
        __builtin_amdgcn_s_setprio(0);
        __builtin_amdgcn_s_barrier();

        cur += 1; if (cur >= 3) cur -= 3;
    }

    // EPI3: hoist per-row sigmoid
    float sgv[4][4];
    if (EPI == 3) {
#pragma unroll
        for (int mi = 0; mi < 4; mi++)
#pragma unroll
            for (int r = 0; r < 4; r++) {
                long row = m0 + wm + mi * 16 + quad * 4 + r;
                sgv[mi][r] = fsig(p.gate_pre[row * 8 + z] + bf2f(p.bgate[z]));
            }
    }

    // Epilogue: D row = quad*4+reg, col = lane&15
#pragma unroll
    for (int mi = 0; mi < 4; mi++) {
#pragma unroll
        for (int ni = 0; ni < 2; ni++) {
            const int mg = m0 + wm + mi * 16 + quad * 4;
            const int ng = n0 + wn + ni * 16 + fr;
#pragma unroll
            for (int r = 0; r < 4; r++) {
                float v = acc[mi][ni][r];
                const long row = mg + r;
                if (EPI == 1) {        // tanh(acc+add+bias) -> bf16   [link->fhs]
                    float ad = bf2f(p.add[z * p.addOff + row * p.ldadd + ng]);
                    v = ftanh(v + ad + bf2f(p.bias[p.biasOff[z] + ng]));
                    ((u16*)p.C)[p.cOff[z] + row * p.ldc + ng] = f2bf(v);
                } else if (EPI == 3) { // sig(gate)*tanh(acc+bias)     [upd]
                    v = ftanh(v + bf2f(p.bias[p.biasOff[z] + ng])) * sgv[mi][r];
                    ((u16*)p.C)[p.cOff[z] + row * p.ldc + ng] = f2bf(v);
                } else if (EPI == 6) { // (acc+bias) -> bf16            [cin]
                    v = v + bf2f(p.bias[p.biasOff[z] + ng]);
                    ((u16*)p.C)[p.cOff[z] + row * p.ldc + ng] = f2bf(v);
                } else {               // EPI 7: tanh(acc+add) -> bf16  [f0]
                    float ad = bf2f(p.add[row * p.ldadd + ng]);
                    v = ftanh(v + ad);
                    ((u16*)p.C)[row * p.ldc + ng] = f2bf(v);
                }
            }
        }
    }
}

// ---------------------------------------------------------------------------
// Fused GRU-GEMM — R9-verified 3-phase fine-interleaved schedule (52 us,
// 496 TF). 128x128 block, 8 waves (2Mx4N, 512 thr), 1 block/CU, 3-buf W +
// 2-buf A (88 KB), counted vmcnt never 0 in loop, setprio around MFMA.
// FROZEN — do not touch without within-probe A/B.
// ---------------------------------------------------------------------------
struct GGP {
    const u16* fhs_in;    // [b][s][1024]  (feats | hs_b)
    u16* fhs_out;         // write hs_b' at [b][s][512+w]
    const u16* Wcat;      // [s][1536][1024]
    const u16* b_ih;      // [s][1536]
    const u16* b_hh;      // [s][1536]
    u16* prism;           // [b][s][512]
    float* gate_pre;      // [b][8]  (atomicAdd, pre-zeroed)
    const u16* Wg;        // [s][512]
    const u16* phase;     // [s][512]
    const u16* pgain;     // [s][512]
};

__global__ __launch_bounds__(512, 2) void grug_k(GGP p) {
    __shared__ __align__(16) u16 sA[2][128 * 32];       // 16 KB
    __shared__ __align__(16) u16 sW[3][3][128 * 32];    // 72 KB
    const int t    = threadIdx.x;
    const int lane = t & 63;
    const int wv   = t >> 6;           // 0..7
    // XCD-group swizzle (grid (32,8)): s = wgid%8 -> one s per XCD.
    const int wgid = blockIdx.x + (blockIdx.y << 5);
    const int s    = wgid & 7;
    const int idx  = wgid >> 3;        // 0..31
    const int w0   = (idx & 3) * 128;
    const int m0   = (idx >> 2) * 128;
    const int fr   = lane & 15;
    const int quad = lane >> 4;
    const int wm   = (wv & 1) * 64;    // wave's m-range (64 rows of 128)
    const int wn   = (wv >> 1) * 32;   // wave's n-range (32 cols of 128)

    const u16* Ab = p.fhs_in + (long)m0 * 8192 + (long)s * 1024;
    const u16* Wb = p.Wcat + (long)s * 1536 * 1024;

    f32x4 acc[4][4][2];   // [q: r,z,inn,hn][mi 0..3][ni 0..1]
#pragma unroll
    for (int q = 0; q < 4; q++)
#pragma unroll
        for (int mi = 0; mi < 4; mi++)
#pragma unroll
            for (int ni = 0; ni < 2; ni++) acc[q][mi][ni] = (f32x4){0.f,0.f,0.f,0.f};

    const int arow = t >> 2, ac4 = t & 3, asrc = ac4 ^ ((arow >> 1) & 3);

    auto stageA = [&](int buf, int kt) {
        gload_lds16(Ab + (long)arow * 8192 + kt * 32 + asrc * 8, &sA[buf][t * 8]);
    };
    auto stageWq = [&](int buf, int kt, int q) {
        long g = (long)(q * 512 + w0 + arow);
        gload_lds16(Wb + g * 1024 + kt * 32 + asrc * 8, &sW[buf][q][t * 8]);
    };

    // Prologue: A(0)+W(0) must land; W(1) stays in flight.  queue: A0,W0x3,W1x3
    stageA(0, 0);
    stageWq(0, 0, 0); stageWq(0, 0, 1); stageWq(0, 0, 2);
    stageWq(1, 1, 0); stageWq(1, 1, 1); stageWq(1, 1, 2);
    asm volatile("s_waitcnt vmcnt(3)" ::: "memory");
    __builtin_amdgcn_s_barrier();

    int aCur = 0, wCur = 0;
    for (int kt = 0; kt < 32; ++kt) {
        const int aNxt = aCur ^ 1;
        int wNx2 = wCur + 2; if (wNx2 >= 3) wNx2 -= 3;
        short8 aF[4], bF0[2], bF1[2], bF2[2];

        // ---------------- P1: aF + bF0 ----------------
#pragma unroll
        for (int mi = 0; mi < 4; mi++) {
            int row = wm + mi * 16 + fr;
            aF[mi] = *(const short8*)&sA[aCur][row * 32 + ((quad ^ ((row >> 1) & 3)) & 3) * 8];
        }
#pragma unroll
        for (int ni = 0; ni < 2; ni++) {
            int row = wn + ni * 16 + fr;
            bF0[ni] = *(const short8*)&sW[wCur][0][row * 32 + ((quad ^ ((row >> 1) & 3)) & 3) * 8];
        }
        if (kt + 1 < 32) stageA(aNxt, kt + 1);
        if (kt + 2 < 32) stageWq(wNx2, kt + 2, 0);
        __builtin_amdgcn_s_barrier();
        asm volatile("s_waitcnt lgkmcnt(0)" ::: "memory");
        __builtin_amdgcn_s_setprio(1);
#pragma unroll
        for (int mi = 0; mi < 4; mi++)
#pragma unroll
            for (int ni = 0; ni < 2; ni++)
                acc[0][mi][ni] = __builtin_amdgcn_mfma_f32_16x16x32_bf16(aF[mi], bF0[ni], acc[0][mi][ni], 0, 0, 0);
        __builtin_amdgcn_s_setprio(0);
        __builtin_amdgcn_s_barrier();

        // ---------------- P2: bF1 ----------------
#pragma unroll
        for (int ni = 0; ni < 2; ni++) {
            int row = wn + ni * 16 + fr;
            bF1[ni] = *(const short8*)&sW[wCur][1][row * 32 + ((quad ^ ((row >> 1) & 3)) & 3) * 8];
        }
        if (kt + 2 < 32) stageWq(wNx2, kt + 2, 1);
        __builtin_amdgcn_s_barrier();
        asm volatile("s_waitcnt lgkmcnt(0)" ::: "memory");
        __builtin_amdgcn_s_setprio(1);
#pragma unroll
        for (int mi = 0; mi < 4; mi++)
#pragma unroll
            for (int ni = 0; ni < 2; ni++)
                acc[1][mi][ni] = __builtin_amdgcn_mfma_f32_16x16x32_bf16(aF[mi], bF1[ni], acc[1][mi][ni], 0, 0, 0);
        __builtin_amdgcn_s_setprio(0);
        __builtin_amdgcn_s_barrier();

        // ---------------- P3: bF2 (+ counted vmcnt, once per kt) ----------------
#pragma unroll
        for (int ni = 0; ni < 2; ni++) {
            int row = wn + ni * 16 + fr;
            bF2[ni] = *(const short8*)&sW[wCur][2][row * 32 + ((quad ^ ((row >> 1) & 3)) & 3) * 8];
        }
        if (kt + 2 < 32) stageWq(wNx2, kt + 2, 2);
        if (kt < 30)       asm volatile("s_waitcnt vmcnt(3) lgkmcnt(0)" ::: "memory");
        else if (kt == 30) asm volatile("s_waitcnt vmcnt(0) lgkmcnt(0)" ::: "memory");
        else               asm volatile("s_waitcnt lgkmcnt(0)" ::: "memory");
        __builtin_amdgcn_s_setprio(1);
        if (kt < 16) {
#pragma unroll
            for (int mi = 0; mi < 4; mi++)
#pragma unroll
                for (int ni = 0; ni < 2; ni++)
                    acc[2][mi][ni] = __builtin_amdgcn_mfma_f32_16x16x32_bf16(aF[mi], bF2[ni], acc[2][mi][ni], 0, 0, 0);
        } else {
#pragma unroll
            for (int mi = 0; mi < 4; mi++)
#pragma unroll
                for (int ni = 0; ni < 2; ni++)
                    acc[3][mi][ni] = __builtin_amdgcn_mfma_f32_16x16x32_bf16(aF[mi], bF2[ni], acc[3][mi][ni], 0, 0, 0);
        }
        __builtin_amdgcn_s_setprio(0);
        __builtin_amdgcn_s_barrier();

        aCur = aNxt;
        wCur += 1; if (wCur >= 3) wCur -= 3;
    }

    // Epilogue: ni-outer so the 9 per-column params load once per column.
    const u16* bih = p.b_ih + (long)s * 1536;
    const u16* bhh = p.b_hh + (long)s * 1536;
    float gp[4][4];
#pragma unroll
    for (int mi = 0; mi < 4; mi++)
#pragma unroll
        for (int r = 0; r < 4; r++) gp[mi][r] = 0.f;

#pragma unroll
    for (int ni = 0; ni < 2; ni++) {
        const int col = w0 + wn + ni * 16 + fr;          // w in [0,512)
        const float br  = bf2f(bih[col])        + bf2f(bhh[col]);
        const float bz  = bf2f(bih[512 + col])  + bf2f(bhh[512 + col]);
        const float bin = bf2f(bih[1024 + col]);
        const float bhn = bf2f(bhh[1024 + col]);
        const float ph  = bf2f(p.phase[s * 512 + col]);
        const float gain = fsoftplus(bf2f(p.pgain[s * 512 + col]));
        const float wg  = bf2f(p.Wg[s * 512 + col]);
#pragma unroll
        for (int mi = 0; mi < 4; mi++) {
#pragma unroll
            for (int r = 0; r < 4; r++) {
                const long b = m0 + wm + mi * 16 + quad * 4 + r;
                float rv = fsig(acc[0][mi][ni][r] + br);
                float zv = fsig(acc[1][mi][ni][r] + bz);
                float nv = ftanh(acc[2][mi][ni][r] + bin + rv * (acc[3][mi][ni][r] + bhn));
                float hold = bf2f(p.fhs_in[b * 8192 + s * 1024 + 512 + col]);
                float hv = (1.f - zv) * nv + zv * hold;
                p.fhs_out[b * 8192 + s * 1024 + 512 + col] = f2bf(hv);
                float c = __cosf(hv + ph);
                p.prism[b * 4096 + s * 512 + col] = f2bf(c * c * gain);
                gp[mi][r] += wg * hv;
            }
        }
    }
    // reduce over fr (16 lanes within quad), then one atomic per row
#pragma unroll
    for (int m = 1; m < 16; m <<= 1)
#pragma unroll
        for (int mi = 0; mi < 4; mi++)
#pragma unroll
            for (int r = 0; r < 4; r++) gp[mi][r] += __shfl_xor(gp[mi][r], m, 64);
    if (fr == 0) {
#pragma unroll
        for (int mi = 0; mi < 4; mi++)
#pragma unroll
            for (int r = 0; r < 4; r++) {
                long b = m0 + wm + mi * 16 + quad * 4 + r;
                atomicAdd(&p.gate_pre[b * 8 + s], gp[mi][r]);
            }
    }
}

// ---------------------------------------------------------------------------
// Encode: masked mean / masked max / last token -> cat [B,1536]
// ---------------------------------------------------------------------------
__global__ __launch_bounds__(256) void encode_k(const int* __restrict__ x,
                                                const u16* __restrict__ embed,
                                                u16* __restrict__ cat) {
    __shared__ int toks[128];
    __shared__ int cnt_s;
    const int b = blockIdx.x, t = threadIdx.x;
    if (t < 128) toks[t] = x[b * 128 + t];
    __syncthreads();
    if (t == 0) {
        int c = 0;
        for (int l = 0; l < 128; l++) c += (toks[l] != 0);
        cnt_s = c;
    }
    __syncthreads();
    const int cnt = cnt_s;
    const int lastTok = toks[cnt > 0 ? cnt - 1 : 0];
    for (int w = t; w < 512; w += 256) {
        float sum = 0.f, mx = -10000.f;
        for (int l = 0; l < 128; l++) {
            int tok = toks[l];
            if (tok != 0) {
                float e = bf2f(embed[tok * 512 + w]);
                sum += e;
                mx = fmaxf(mx, e);
            }
        }
        float mean = sum / (float)(cnt > 0 ? cnt : 1);
        float last = bf2f(embed[lastTok * 512 + w]);
        cat[(long)b * 1536 + w]        = f2bf(mean);
        cat[(long)b * 1536 + 512 + w]  = f2bf(mx);
        cat[(long)b * 1536 + 1024 + w] = f2bf(last);
    }
}

// ---------------------------------------------------------------------------
// delta = sum_s upd / sqrt(S);  h = tanh(h*decay + delta); h_b = bf16(h)
// Also zeroes gate_pre for the NEXT step's grug (replaces 12 memset
// dispatches; ordering: grug fills -> upd-gemm reads -> hupd zeroes).
// ---------------------------------------------------------------------------
__global__ __launch_bounds__(256) void hupd_k(const u16* __restrict__ upd,
                                              float* __restrict__ h,
                                              u16* __restrict__ h_b,
                                              const u16* __restrict__ decay_p,
                                              float* __restrict__ gate_pre) {
    const int idx = blockIdx.x * 256 + threadIdx.x;
    if (idx < 8192) gate_pre[idx] = 0.f;
    const int b = idx >> 9, w = idx & 511;
    const long base = (long)b * 4096 + w;
    float dsum = 0.f;
#pragma unroll
    for (int s = 0; s < 8; s++) dsum += bf2f(upd[base + s * 512]);
    const float decay = fsig(bf2f(decay_p[0]));
    const float hv = ftanh(h[idx] * decay + dsum * 0.35355339059327373f);
    h[idx] = hv;
    h_b[idx] = f2bf(hv);
}

// ---------------------------------------------------------------------------
// Final head; output dtype follows detected input dtype.
// ---------------------------------------------------------------------------
__global__ __launch_bounds__(64) void out_k(const float* __restrict__ h,
                                            const u16* __restrict__ Wout,
                                            const u16* __restrict__ bout,
                                            void* __restrict__ out,
                                            const int* __restrict__ flag) {
    const int b = blockIdx.x, lane = threadIdx.x;
    const int isbf = *flag;
    for (int j = 0; j < 10; j++) {
        float p = 0.f;
#pragma unroll
        for (int k = 0; k < 8; k++) {
            int w = lane + k * 64;
            p += h[(long)b * 512 + w] * bf2f(Wout[j * 512 + w]);
        }
#pragma unroll
        for (int off = 32; off; off >>= 1) p += __shfl_down(p, off, 64);
        if (lane == 0) {
            float val = p + bf2f(bout[j]);
            if (isbf) ((u16*)out)[b * 10 + j] = f2bf(val);
            else      ((float*)out)[b * 10 + j] = val;
        }
    }
}

// ---------------------------------------------------------------------------
extern "C" void kernel_launch(void* const* d_in, const int* in_sizes, int n_in,
                              void* d_out, int out_size, void* d_ws, size_t ws_size,
                              hipStream_t stream) {
    (void)n_in; (void)out_size; (void)ws_size;
    const int* x = (const int*)d_in[0];

    char* pp = (char*)d_ws;
    auto carve = [&](size_t n) { char* r = pp; pp += (n + 255) & ~(size_t)255; return (void*)r; };

    // canonical bf16 parameter block (~44 MB)
    CT ct;
    size_t ctot = 0;
    for (int i = 0; i < 20; i++) {
        ct.src[i] = d_in[i + 1];
        ct.n[i]   = in_sizes[i + 1];
        ct.off[i] = (int)ctot;
        ctot += ((size_t)in_sizes[i + 1] + 15) & ~(size_t)15;
    }
    u16* canon = (u16*)carve(ctot * 2);
    const u16* embed  = canon + ct.off[0];
    const u16* W_mix  = canon + ct.off[1];
    const u16* b_mix  = canon + ct.off[2];
    const u16* W_in   = canon + ct.off[3];
    const u16* b_in   = canon + ct.off[4];
    const u16* W_link = canon + ct.off[5];
    const u16* b_link = canon + ct.off[6];
    const u16* W_ih   = canon + ct.off[7];
    const u16* b_ih   = canon + ct.off[8];
    const u16* W_hh   = canon + ct.off[9];
    const u16* b_hh   = canon + ct.off[10];
    const u16* W_gate = canon + ct.off[11];
    const u16* b_gate = canon + ct.off[12];
    const u16* phase  = canon + ct.off[13];
    const u16* pgain  = canon + ct.off[14];
    const u16* W_delta= canon + ct.off[15];
    const u16* b_delta= canon + ct.off[16];
    const u16* decayp = canon + ct.off[17];
    const u16* W_out  = canon + ct.off[18];
    const u16* b_out  = canon + ct.off[19];

    int*   flag   = (int*)  carve(256);
    u16*   Wcat   = (u16*)  carve((size_t)8 * 1536 * 1024 * 2);  // 25 MB
    u16*   cat    = (u16*)  carve((size_t)1024 * 1536 * 2);
    u16*   h_b    = (u16*)  carve((size_t)1024 * 512 * 2);
    u16*   summ_b = (u16*)  carve((size_t)1024 * 512 * 2);
    float* h      = (float*)carve((size_t)1024 * 512 * 4);
    u16*   cin    = (u16*)  carve((size_t)1024 * 4096 * 2);
    u16*   f0     = (u16*)  carve((size_t)1024 * 4096 * 2);
    u16*   fhs0   = (u16*)  carve((size_t)1024 * 8192 * 2);      // 16 MB
    u16*   fhs1   = (u16*)  carve((size_t)1024 * 8192 * 2);      // 16 MB
    u16*   prism  = (u16*)  carve((size_t)1024 * 4096 * 2);
    u16*   upd    = (u16*)  carve((size_t)1024 * 4096 * 2);
    float* gate_pre = (float*)carve((size_t)1024 * 8 * 4);

    (void)hipMemsetAsync(fhs0, 0, (size_t)1024 * 8192 * 2, stream);
    (void)hipMemsetAsync(fhs1, 0, (size_t)1024 * 8192 * 2, stream);
    (void)hipMemsetAsync(gate_pre, 0, (size_t)1024 * 8 * 4, stream);

    detect_k<<<dim3(1), dim3(256), 0, stream>>>((const u16*)d_in[1], flag);
    conv_k<<<dim3(1024), dim3(256), 0, stream>>>(ct, canon, flag);
    pack_k<<<dim3(3072), dim3(256), 0, stream>>>(W_ih, W_hh, Wcat);
    encode_k<<<dim3(1024), dim3(256), 0, stream>>>(x, embed, cat);

    {   // summary = tanh(cat @ W_mix^T + b_mix) -> h_b, summ_b, h
        GP p{}; p.A = cat; p.lda = 1536; p.Bw = W_mix; p.ldb = 1536;
        p.bias = b_mix; p.C = h_b; p.ldc = 512; p.C2 = h; p.C3 = summ_b;
        p.K = 1536; p.nt = 4;
        gemm_k<4, 64, 0><<<dim3(4, 16, 1), dim3(256), 0, stream>>>(p);
    }
    {   // cin = summary @ W_in[:, :, 512:]^T + b_in   [gemm8 BK=64]
        GP p{}; p.A = summ_b; p.lda = 512; p.Bw = W_in + 512; p.ldb = 1024;
        p.bias = b_in; p.C = cin; p.ldc = 4096; p.K = 512; p.nt = 32;
        gemm8_k<6><<<dim3(32, 8, 1), dim3(512), 0, stream>>>(p);
    }

    for (int step = 0; step < 12; ++step) {
        u16* fhs_cur = (step & 1) ? fhs1 : fhs0;
        u16* fhs_nxt = (step & 1) ? fhs0 : fhs1;
        {   // f0 = tanh(h @ W_in[:, :, :512]^T + cin)   [gemm8 BK=64]
            GP p{}; p.A = h_b; p.lda = 512; p.Bw = W_in; p.ldb = 1024;
            p.add = cin; p.ldadd = 4096; p.C = f0; p.ldc = 4096;
            p.K = 512; p.nt = 32;
            gemm8_k<7><<<dim3(32, 8, 1), dim3(512), 0, stream>>>(p);
        }
        {   // feats = tanh(f0 + prev @ W_link^T + b_link) -> fhs_cur[:, s, 0:512]
            GP p{}; p.A = f0; p.lda = 4096;
            for (int s = 0; s < 8; s++) p.aOff[s] = (long)((s + 7) & 7) * 512;
            p.Bw = W_link; p.ldb = 512;
            for (int s = 0; s < 8; s++) p.bwOff[s] = (long)s * 512 * 512;
            p.bias = b_link;
            for (int s = 0; s < 8; s++) p.biasOff[s] = (long)s * 512;
            p.add = f0; p.ldadd = 4096; p.addOff = 512;
            p.C = fhs_cur; p.ldc = 8192;
            for (int s = 0; s < 8; s++) p.cOff[s] = (long)s * 1024;
            p.K = 512; p.nt = 4;
            gemm8_k<1><<<dim3(32, 8, 1), dim3(512), 0, stream>>>(p);
        }
        {   // fused GRU-GEMM (R9-frozen 3-phase)
            GGP g{};
            g.fhs_in = fhs_cur; g.fhs_out = fhs_nxt; g.Wcat = Wcat;
            g.b_ih = b_ih; g.b_hh = b_hh; g.prism = prism; g.gate_pre = gate_pre;
            g.Wg = W_gate; g.phase = phase; g.pgain = pgain;
            grug_k<<<dim3(32, 8, 1), dim3(512), 0, stream>>>(g);
        }
        {   // upd = sig(gate)*tanh(prism @ W_delta^T + b_delta) -> bf16
            GP p{}; p.A = prism; p.lda = 4096;
            for (int s = 0; s < 8; s++) p.aOff[s] = (long)s * 512;
            p.Bw = W_delta; p.ldb = 512;
            for (int s = 0; s < 8; s++) p.bwOff[s] = (long)s * 512 * 512;
            p.bias = b_delta;
            for (int s = 0; s < 8; s++) p.biasOff[s] = (long)s * 512;
            p.gate_pre = gate_pre; p.bgate = b_gate;
            p.C = upd; p.ldc = 4096;
            for (int s = 0; s < 8; s++) p.cOff[s] = (long)s * 512;
            p.K = 512; p.nt = 4;
            gemm8_k<3><<<dim3(32, 8, 1), dim3(512), 0, stream>>>(p);
        }
        hupd_k<<<dim3(2048), dim3(256), 0, stream>>>(upd, h, h_b, decayp, gate_pre);
    }

    out_k<<<dim3(1024), dim3(64), 0, stream>>>(h, W_out, b_out, d_out, flag);
}